// Round 7
// baseline (141.357 us; speedup 1.0000x reference)
//
#include <hip/hip_runtime.h>
#include <hip/hip_bf16.h>

#define NN 4096
#define NUPPER 528           // upper 128-blocks per operand
#define NLOWER 496
#define NT2 16               // 256-tiles per side
#define NUP2 136             // upper 256-tiles
#define BLK_ELEMS 16384      // 128*128
#define TILE2_ELEMS 65536    // 256*256
#define ZB_ELEMS 16384       // 32 KB zero region

typedef __bf16 v8bf __attribute__((ext_vector_type(8)));
typedef __bf16 v4bf __attribute__((ext_vector_type(4)));
typedef float  v4f  __attribute__((ext_vector_type(4)));

typedef __attribute__((address_space(1))) const unsigned int* as1p;
typedef __attribute__((address_space(3))) unsigned int* as3p;
#define GLOAD16(DST_LDS, SRC_G) \
    __builtin_amdgcn_global_load_lds((as1p)(const void*)(SRC_G), (as3p)(void*)(DST_LDS), 16, 0, 0)

// ---------------- prep: bf16-pack A, bf16-transpose-pack B, zero C/Zb -------
__global__ __launch_bounds__(256)
void trimm_prep(const float* __restrict__ A, const float* __restrict__ B,
                float* __restrict__ C,
                __bf16* __restrict__ Apk, __bf16* __restrict__ Bpk,
                __bf16* __restrict__ Zb) {
    const int p = blockIdx.x;
    const int t = threadIdx.x;
    __shared__ __bf16 Ls[128][132];

    if (p < NUPPER) {
        // ---- A block (bi, q): idx = bi*32 - bi(bi-1)/2 + (q-bi) ----
        int bi = 0;
        while ((bi + 1) * 32 - ((bi + 1) * bi) / 2 <= p) ++bi;
        const int base = bi * 32 - (bi * (bi - 1)) / 2;
        const int q = bi + (p - base);
        const float* src = A + (long)bi * 128 * NN + (long)q * 128;
        __bf16* dst = Apk + (long)p * BLK_ELEMS;
        #pragma unroll
        for (int i = 0; i < 16; ++i) {
            int s = i * 256 + t, r = s >> 5, c4 = (s & 31) << 2;
            v4f v = __builtin_nontemporal_load(
                reinterpret_cast<const v4f*>(&src[(long)r * NN + c4]));
            v4bf pk;
            pk[0] = (__bf16)v[0]; pk[1] = (__bf16)v[1];
            pk[2] = (__bf16)v[2]; pk[3] = (__bf16)v[3];
            *reinterpret_cast<v4bf*>(&dst[r * 128 + c4]) = pk;
        }
        return;
    }
    if (p < 2 * NUPPER) {
        // ---- B block (q, bj) -> Bpk[n][k] transposed, idx bj*(bj+1)/2+q ----
        const int p2 = p - NUPPER;
        int bj = 0;
        while (((bj + 1) * (bj + 2)) / 2 <= p2) ++bj;
        const int q = p2 - (bj * (bj + 1)) / 2;
        const float* src = B + (long)q * 128 * NN + (long)bj * 128;
        __bf16* dst = Bpk + (long)p2 * BLK_ELEMS;
        #pragma unroll
        for (int i = 0; i < 16; ++i) {
            int s = i * 256 + t, k = s >> 5, n4 = (s & 31) << 2;
            v4f v = __builtin_nontemporal_load(
                reinterpret_cast<const v4f*>(&src[(long)k * NN + n4]));
            Ls[k][n4 + 0] = (__bf16)v[0]; Ls[k][n4 + 1] = (__bf16)v[1];
            Ls[k][n4 + 2] = (__bf16)v[2]; Ls[k][n4 + 3] = (__bf16)v[3];
        }
        __syncthreads();
        #pragma unroll
        for (int i = 0; i < 8; ++i) {
            int n = i * 16 + (t >> 4), k0 = (t & 15) << 3;
            v8bf o;
            #pragma unroll
            for (int j = 0; j < 8; ++j) o[j] = Ls[k0 + j][n];
            *reinterpret_cast<v8bf*>(&dst[n * 128 + k0]) = o;
        }
        return;
    }
    if (p < 2 * NUPPER + NLOWER) {
        // ---- zero-fill strictly-lower C tile (streaming) ----
        const int z = p - 2 * NUPPER;
        int bi = 1;
        while (((bi + 1) * bi) / 2 <= z) ++bi;
        const int bj = z - (bi * (bi - 1)) / 2;
        const long brow = (long)bi * 128, bcol = (long)bj * 128;
        const v4f zv = (v4f){0.f, 0.f, 0.f, 0.f};
        #pragma unroll
        for (int i = 0; i < 16; ++i) {
            int s = i * 256 + t, r = s >> 5, c4 = (s & 31) << 2;
            __builtin_nontemporal_store(zv,
                reinterpret_cast<v4f*>(&C[(brow + r) * NN + bcol + c4]));
        }
        return;
    }
    // ---- zero the 32 KB redirect region ----
    const v4bf zb = (v4bf){(__bf16)0.f, (__bf16)0.f, (__bf16)0.f, (__bf16)0.f};
    #pragma unroll
    for (int i = 0; i < 16; ++i)
        *reinterpret_cast<v4bf*>(&Zb[(i * 256 + t) * 4]) = zb;
}

// ------ main MFMA kernel: 256^2 tile, 512 thr, BK=64, gload_lds + swizzle ---
__global__ __launch_bounds__(512, 2)
void trimm_mm(const __bf16* __restrict__ Apk, const __bf16* __restrict__ Bpk,
              const __bf16* __restrict__ Zb,
              float* __restrict__ C, __bf16* __restrict__ part, int umax) {
    const int id = blockIdx.x;
    const int t  = threadIdx.x;

    // map id -> (d2 desc, bi2, chunk c); slot base for partials
    int rem = id, d2, S, sb = 0;
    for (d2 = NT2 - 1;; --d2) {
        S = (d2 + umax) / umax;                  // ceil((d2+1)/umax)
        int cnt = (NT2 - d2) * S;
        if (rem < cnt) break;
        rem -= cnt;
        sb += (NT2 - d2) * (S - 1);
    }
    const int bi2 = rem / S, c = rem % S;
    const int bj2 = bi2 + d2;
    const int U = d2 + 1;
    const int ubase = U / S, uremu = U % S;
    const int units = ubase + ((c < uremu) ? 1 : 0);
    const int qoff  = c * ubase + ((c < uremu) ? c : uremu);
    const int nt    = units * 4;                         // BK=64 steps
    const long kstart = (long)(bi2 + qoff) * 256;

    __shared__ __bf16 AsF[2][16384];   // logical [256 rows][64 k], swizzled
    __shared__ __bf16 BsF[2][16384];

    const int lane = t & 63, wave = t >> 6;              // 8 waves
    const int wr = (wave >> 2) << 7;                     // wave row: 0,128
    const int wc = (wave & 3) << 6;                      // wave col: 0..192
    const int l15 = lane & 15, g = lane >> 4;
    const int swz = (l15 & 7) << 3;
    const int srow8 = lane >> 3;
    const int sslot = ((lane & 7) ^ srow8) << 3;

    v4f acc[8][4];
    #pragma unroll
    for (int mf = 0; mf < 8; ++mf)
        #pragma unroll
        for (int nf = 0; nf < 4; ++nf)
            acc[mf][nf] = (v4f){0.f, 0.f, 0.f, 0.f};

    #define STAGE(BUF, TK)                                                    \
        {                                                                     \
            const long kk  = kstart + (long)(TK) * 64;                        \
            const int q128 = (int)(kk >> 7);                                  \
            const int kin  = (int)kk & 127;                                   \
            _Pragma("unroll")                                                 \
            for (int i = 0; i < 4; ++i) {                                     \
                const int seg  = (wave << 2) + i;        /* 0..31 */          \
                const int half = seg >> 4;                                    \
                const int rloc = ((seg & 15) << 3) + srow8;                   \
                const long lofs = ((long)rloc << 7) + kin + sslot;            \
                const int bia = bi2 * 2 + half;                               \
                const __bf16* asrc = (q128 >= bia)                            \
                    ? Apk + (((long)(bia * 32 - (bia * (bia - 1)) / 2 - bia   \
                                     + q128)) << 14) + lofs                   \
                    : Zb + lofs;                                              \
                GLOAD16(&AsF[BUF][seg << 9], asrc);                           \
                const int bjb = bj2 * 2 + half;                               \
                const __bf16* bsrc = (q128 <= bjb)                            \
                    ? Bpk + (((long)((bjb * (bjb + 1)) / 2 + q128)) << 14)    \
                          + lofs                                              \
                    : Zb + lofs;                                              \
                GLOAD16(&BsF[BUF][seg << 9], bsrc);                           \
            }                                                                 \
        }

    STAGE(0, 0);
    __syncthreads();

    int cur = 0;
    for (int tk = 0; tk < nt; ++tk) {
        if (tk + 1 < nt) STAGE(cur ^ 1, tk + 1);

        #pragma unroll
        for (int kc = 0; kc < 2; ++kc) {
            v8bf af[8], bfv[4];
            #pragma unroll
            for (int nf = 0; nf < 4; ++nf) {
                int n = wc + nf * 16 + l15;
                bfv[nf] = *reinterpret_cast<const v8bf*>(
                    &BsF[cur][((n << 6) + kc * 32 + g * 8) ^ swz]);
            }
            #pragma unroll
            for (int mf = 0; mf < 8; ++mf) {
                int row = wr + mf * 16 + l15;
                af[mf] = *reinterpret_cast<const v8bf*>(
                    &AsF[cur][((row << 6) + kc * 32 + g * 8) ^ swz]);
            }
            #pragma unroll
            for (int mf = 0; mf < 8; ++mf)
                #pragma unroll
                for (int nf = 0; nf < 4; ++nf)
                    acc[mf][nf] = __builtin_amdgcn_mfma_f32_16x16x32_bf16(
                        af[mf], bfv[nf], acc[mf][nf], 0, 0, 0);
        }
        __syncthreads();   // drains vmcnt(0): next tile staged, reads done
        cur ^= 1;
    }
    #undef STAGE

    // epilogue: C/D layout col=lane&15, row=(lane>>4)*4+reg
    if (c == 0) {
        float* outp = C + (long)bi2 * 256 * NN + (long)bj2 * 256;
        const bool merged = (S > 1);
        #pragma unroll
        for (int mf = 0; mf < 8; ++mf)
            #pragma unroll
            for (int nf = 0; nf < 4; ++nf) {
                int row = wr + mf * 16 + g * 4;
                int col = wc + nf * 16 + l15;
                #pragma unroll
                for (int r = 0; r < 4; ++r) {
                    float* p = &outp[(long)(row + r) * NN + col];
                    if (merged) *p = acc[mf][nf][r];
                    else        __builtin_nontemporal_store(acc[mf][nf][r], p);
                }
            }
    } else {
        __bf16* pp = part + (long)(sb + bi2 * (S - 1) + (c - 1)) * TILE2_ELEMS;
        #pragma unroll
        for (int mf = 0; mf < 8; ++mf)
            #pragma unroll
            for (int nf = 0; nf < 4; ++nf) {
                int row = wr + mf * 16 + g * 4;
                int col = wc + nf * 16 + l15;
                #pragma unroll
                for (int r = 0; r < 4; ++r)
                    pp[(row + r) * 256 + col] = (__bf16)acc[mf][nf][r];
            }
    }
}

// ---------------- merge: C += partials (fixed order), 256-tiles -------------
__global__ __launch_bounds__(256)
void trimm_merge(float* __restrict__ C, const __bf16* __restrict__ part, int umax) {
    int rem = blockIdx.x;
    const int t = threadIdx.x;
    int d2, S, sb = 0;
    for (d2 = NT2 - 1;; --d2) {
        S = (d2 + umax) / umax;
        int cnt = NT2 - d2;
        if (rem < cnt) break;
        rem -= cnt;
        sb += (NT2 - d2) * (S - 1);
    }
    if (S == 1) return;
    const int bi2 = rem, bj2 = bi2 + d2;
    const int ns = S - 1;
    const __bf16* pp = part + (long)(sb + bi2 * ns) * TILE2_ELEMS;
    float* cp = C + (long)bi2 * 256 * NN + (long)bj2 * 256;

    for (int i = 0; i < 32; ++i) {
        int e = (i * 256 + t) * 8;
        int r = e >> 8, c8 = e & 255;
        v4f lo = *reinterpret_cast<v4f*>(&cp[(long)r * NN + c8]);
        v4f hi = *reinterpret_cast<v4f*>(&cp[(long)r * NN + c8 + 4]);
        for (int q = 0; q < ns; ++q) {
            v8bf w = *reinterpret_cast<const v8bf*>(
                &pp[(long)q * TILE2_ELEMS + r * 256 + c8]);
            lo[0] += (float)w[0]; lo[1] += (float)w[1];
            lo[2] += (float)w[2]; lo[3] += (float)w[3];
            hi[0] += (float)w[4]; hi[1] += (float)w[5];
            hi[2] += (float)w[6]; hi[3] += (float)w[7];
        }
        __builtin_nontemporal_store(lo, reinterpret_cast<v4f*>(&cp[(long)r * NN + c8]));
        __builtin_nontemporal_store(hi, reinterpret_cast<v4f*>(&cp[(long)r * NN + c8 + 4]));
    }
}

// ---------------- fallback (ws too small): fused convert-stage kernel -------
#define LDST 40
__global__ __launch_bounds__(256)
void trimm_fb(const float* __restrict__ A, const float* __restrict__ B,
              float* __restrict__ C) {
    const int id = blockIdx.x, t = threadIdx.x;
    if (id >= NUPPER) {
        int z = id - NUPPER;
        int bi = 1;
        while (((bi + 1) * bi) / 2 <= z) ++bi;
        int bj = z - (bi * (bi - 1)) / 2;
        const long brow = (long)bi * 128, bcol = (long)bj * 128;
        const v4f zv = (v4f){0.f, 0.f, 0.f, 0.f};
        #pragma unroll
        for (int i = 0; i < 16; ++i) {
            int s = i * 256 + t, r = s >> 5, c4 = (s & 31) << 2;
            *reinterpret_cast<v4f*>(&C[(brow + r) * NN + bcol + c4]) = zv;
        }
        return;
    }
    int q = (NUPPER - 1) - id;
    int d = 0;
    while (d < 31 && 32 * (d + 1) - (d + 1) * d / 2 <= q) ++d;
    const int bi = q - (32 * d - d * (d - 1) / 2);
    const int bj = bi + d;
    const long brow = (long)bi * 128, bcol = (long)bj * 128;
    __shared__ __bf16 As[128][LDST];
    __shared__ __bf16 Bs[128][LDST];
    const int lane = t & 63, wave = t >> 6;
    const int wm = (wave >> 1) * 64, wn = (wave & 1) * 64;
    const int l15 = lane & 15, g = lane >> 4;
    const int arow = t >> 3, akc = (t & 7) << 2;
    const int bn = t & 31, bkc = (t >> 5) << 2;
    v4f acc[4][4];
    #pragma unroll
    for (int mf = 0; mf < 4; ++mf)
        #pragma unroll
        for (int nf = 0; nf < 4; ++nf) acc[mf][nf] = (v4f){0.f,0.f,0.f,0.f};
    const long k0 = brow;
    const int nt = (d + 1) * 4;
    for (int tk = 0; tk < nt; ++tk) {
        const long kt = k0 + (long)tk * 32;
        #pragma unroll
        for (int i = 0; i < 4; ++i) {
            v4f a4 = *reinterpret_cast<const v4f*>(
                &A[(brow + arow + 32 * i) * NN + kt + akc]);
            v4bf pk;
            pk[0]=(__bf16)a4[0]; pk[1]=(__bf16)a4[1]; pk[2]=(__bf16)a4[2]; pk[3]=(__bf16)a4[3];
            *reinterpret_cast<v4bf*>(&As[arow + 32 * i][akc]) = pk;
        }
        {
            float tmp[4][4];
            #pragma unroll
            for (int jj = 0; jj < 4; ++jj) {
                const float* Brow = B + (kt + bkc + jj) * NN + bcol + bn;
                #pragma unroll
                for (int j = 0; j < 4; ++j) tmp[j][jj] = Brow[32 * j];
            }
            #pragma unroll
            for (int j = 0; j < 4; ++j) {
                v4bf pk;
                pk[0]=(__bf16)tmp[j][0]; pk[1]=(__bf16)tmp[j][1];
                pk[2]=(__bf16)tmp[j][2]; pk[3]=(__bf16)tmp[j][3];
                *reinterpret_cast<v4bf*>(&Bs[bn + 32 * j][bkc]) = pk;
            }
        }
        __syncthreads();
        v8bf af[4], bfr[4];
        #pragma unroll
        for (int mf = 0; mf < 4; ++mf)
            af[mf] = *reinterpret_cast<const v8bf*>(&As[wm + mf*16 + l15][g*8]);
        #pragma unroll
        for (int nf = 0; nf < 4; ++nf)
            bfr[nf] = *reinterpret_cast<const v8bf*>(&Bs[wn + nf*16 + l15][g*8]);
        #pragma unroll
        for (int mf = 0; mf < 4; ++mf)
            #pragma unroll
            for (int nf = 0; nf < 4; ++nf)
                acc[mf][nf] = __builtin_amdgcn_mfma_f32_16x16x32_bf16(
                    af[mf], bfr[nf], acc[mf][nf], 0, 0, 0);
        __syncthreads();
    }
    #pragma unroll
    for (int mf = 0; mf < 4; ++mf)
        #pragma unroll
        for (int nf = 0; nf < 4; ++nf) {
            long row = brow + wm + mf * 16 + g * 4;
            long col = bcol + wn + nf * 16 + l15;
            #pragma unroll
            for (int r = 0; r < 4; ++r)
                C[(row + r) * NN + col] = acc[mf][nf][r];
        }
}

static void split_counts2(int umax, int* nwork, int* slots) {
    int w = 0, s = 0;
    for (int d = 0; d < NT2; ++d) {
        int S = (d + umax) / umax;
        w += (NT2 - d) * S;
        s += (NT2 - d) * (S - 1);
    }
    *nwork = w; *slots = s;
}

extern "C" void kernel_launch(void* const* d_in, const int* in_sizes, int n_in,
                              void* d_out, int out_size, void* d_ws, size_t ws_size,
                              hipStream_t stream) {
    const float* A = (const float*)d_in[0];
    const float* B = (const float*)d_in[1];
    float* C = (float*)d_out;

    const size_t elemsAB = 2UL * NUPPER * BLK_ELEMS;              // bf16 elems
    const size_t needBase = (elemsAB + ZB_ELEMS) * sizeof(__bf16);  // ~33.1 MB

    const int cand[5] = {2, 3, 4, 5, 1000};
    int umax = 0, nwork = 0, slots = 0;
    for (int i = 0; i < 5; ++i) {
        int w, s;
        split_counts2(cand[i], &w, &s);
        size_t need = needBase + (size_t)s * TILE2_ELEMS * sizeof(__bf16);
        if (ws_size >= need) { umax = cand[i]; nwork = w; slots = s; break; }
    }

    if (umax) {
        __bf16* Apk = (__bf16*)d_ws;
        __bf16* Bpk = Apk + (size_t)NUPPER * BLK_ELEMS;
        __bf16* Zb  = Bpk + (size_t)NUPPER * BLK_ELEMS;
        __bf16* part = Zb + ZB_ELEMS;
        trimm_prep<<<dim3(2 * NUPPER + NLOWER + 1), 256, 0, stream>>>(
            A, B, C, Apk, Bpk, Zb);
        trimm_mm<<<dim3(nwork), 512, 0, stream>>>(Apk, Bpk, Zb, C, part, umax);
        if (slots > 0)
            trimm_merge<<<dim3(NUP2), 256, 0, stream>>>(C, part, umax);
    } else {
        trimm_fb<<<dim3(NUPPER + NLOWER), 256, 0, stream>>>(A, B, C);
    }
}

// Round 8
// 114.285 us; speedup vs baseline: 1.2369x; 1.2369x over previous
//
#include <hip/hip_runtime.h>
#include <hip/hip_bf16.h>

#define NN 4096
#define NUPPER 528           // upper 128-blocks per operand
#define NLOWER 496
#define NT2 16               // 256-tiles per side
#define NUP2 136             // upper 256-tiles
#define BLK_ELEMS 16384      // 128*128
#define TILE2_ELEMS 65536    // 256*256
#define ZB_ELEMS 16384       // 32 KB zero region

typedef __bf16 v8bf __attribute__((ext_vector_type(8)));
typedef __bf16 v4bf __attribute__((ext_vector_type(4)));
typedef float  v4f  __attribute__((ext_vector_type(4)));

typedef __attribute__((address_space(1))) const unsigned int* as1p;
typedef __attribute__((address_space(3))) unsigned int* as3p;
#define GLOAD16(DST_LDS, SRC_G) \
    __builtin_amdgcn_global_load_lds((as1p)(const void*)(SRC_G), (as3p)(void*)(DST_LDS), 16, 0, 0)

// ---------------- prep: bf16-pack A, bf16-transpose-pack B, zero C/Zb -------
__global__ __launch_bounds__(256)
void trimm_prep(const float* __restrict__ A, const float* __restrict__ B,
                float* __restrict__ C,
                __bf16* __restrict__ Apk, __bf16* __restrict__ Bpk,
                __bf16* __restrict__ Zb) {
    const int p = blockIdx.x;
    const int t = threadIdx.x;
    __shared__ __bf16 Ls[128][132];

    if (p < NUPPER) {
        int bi = 0;
        while ((bi + 1) * 32 - ((bi + 1) * bi) / 2 <= p) ++bi;
        const int base = bi * 32 - (bi * (bi - 1)) / 2;
        const int q = bi + (p - base);
        const float* src = A + (long)bi * 128 * NN + (long)q * 128;
        __bf16* dst = Apk + (long)p * BLK_ELEMS;
        #pragma unroll
        for (int i = 0; i < 16; ++i) {
            int s = i * 256 + t, r = s >> 5, c4 = (s & 31) << 2;
            v4f v = __builtin_nontemporal_load(
                reinterpret_cast<const v4f*>(&src[(long)r * NN + c4]));
            v4bf pk;
            pk[0] = (__bf16)v[0]; pk[1] = (__bf16)v[1];
            pk[2] = (__bf16)v[2]; pk[3] = (__bf16)v[3];
            *reinterpret_cast<v4bf*>(&dst[r * 128 + c4]) = pk;
        }
        return;
    }
    if (p < 2 * NUPPER) {
        const int p2 = p - NUPPER;
        int bj = 0;
        while (((bj + 1) * (bj + 2)) / 2 <= p2) ++bj;
        const int q = p2 - (bj * (bj + 1)) / 2;
        const float* src = B + (long)q * 128 * NN + (long)bj * 128;
        __bf16* dst = Bpk + (long)p2 * BLK_ELEMS;
        #pragma unroll
        for (int i = 0; i < 16; ++i) {
            int s = i * 256 + t, k = s >> 5, n4 = (s & 31) << 2;
            v4f v = __builtin_nontemporal_load(
                reinterpret_cast<const v4f*>(&src[(long)k * NN + n4]));
            Ls[k][n4 + 0] = (__bf16)v[0]; Ls[k][n4 + 1] = (__bf16)v[1];
            Ls[k][n4 + 2] = (__bf16)v[2]; Ls[k][n4 + 3] = (__bf16)v[3];
        }
        __syncthreads();
        #pragma unroll
        for (int i = 0; i < 8; ++i) {
            int n = i * 16 + (t >> 4), k0 = (t & 15) << 3;
            v8bf o;
            #pragma unroll
            for (int j = 0; j < 8; ++j) o[j] = Ls[k0 + j][n];
            *reinterpret_cast<v8bf*>(&dst[n * 128 + k0]) = o;
        }
        return;
    }
    if (p < 2 * NUPPER + NLOWER) {
        const int z = p - 2 * NUPPER;
        int bi = 1;
        while (((bi + 1) * bi) / 2 <= z) ++bi;
        const int bj = z - (bi * (bi - 1)) / 2;
        const long brow = (long)bi * 128, bcol = (long)bj * 128;
        const v4f zv = (v4f){0.f, 0.f, 0.f, 0.f};
        #pragma unroll
        for (int i = 0; i < 16; ++i) {
            int s = i * 256 + t, r = s >> 5, c4 = (s & 31) << 2;
            __builtin_nontemporal_store(zv,
                reinterpret_cast<v4f*>(&C[(brow + r) * NN + bcol + c4]));
        }
        return;
    }
    const v4bf zb = (v4bf){(__bf16)0.f, (__bf16)0.f, (__bf16)0.f, (__bf16)0.f};
    #pragma unroll
    for (int i = 0; i < 16; ++i)
        *reinterpret_cast<v4bf*>(&Zb[(i * 256 + t) * 4]) = zb;
}

// --- main: 256^2 tile, BK=32, 3-stage ring, counted vmcnt (T3/T4) ----------
__global__ __launch_bounds__(512, 2)
void trimm_mm(const __bf16* __restrict__ Apk, const __bf16* __restrict__ Bpk,
              const __bf16* __restrict__ Zb,
              float* __restrict__ C, __bf16* __restrict__ part, int umax) {
    const int id = blockIdx.x;
    const int t  = threadIdx.x;

    // map id -> (d2 desc, bi2, chunk c); slot base for partials
    int rem = id, d2, S, sb = 0;
    for (d2 = NT2 - 1;; --d2) {
        S = (d2 + umax) / umax;                  // ceil((d2+1)/umax)
        int cnt = (NT2 - d2) * S;
        if (rem < cnt) break;
        rem -= cnt;
        sb += (NT2 - d2) * (S - 1);
    }
    const int bi2 = rem / S, c = rem % S;
    const int bj2 = bi2 + d2;
    const int U = d2 + 1;
    const int ubase = U / S, uremu = U % S;
    const int units = ubase + ((c < uremu) ? 1 : 0);
    const int qoff  = c * ubase + ((c < uremu) ? c : uremu);
    const int nt    = units * 8;                         // BK=32 steps
    const long kstart = (long)(bi2 + qoff) * 256;

    // 3-stage ring: per stage A[256 rows][32 k] + B, slot-rotated layout:
    // physical 8-elem slot sp = (logical slot + (row>>1)) & 3
    __shared__ __bf16 AsF[3][8192];
    __shared__ __bf16 BsF[3][8192];

    const int lane = t & 63, wave = t >> 6;              // 8 waves
    const int wr = (wave >> 2) << 7;                     // 0,128
    const int wc = (wave & 3) << 6;                      // 0..192
    const int l15 = lane & 15, g = lane >> 4;
    const int rdsl = ((g + (l15 >> 1)) & 3) << 3;        // read slot (elems)
    const int lq = lane >> 2, lp = lane & 3;
    const int lsl = (lp - (lq >> 1)) & 3;                // staging logical slot
    const long lsrc = (long)lq * 128 + lsl * 8;          // per-lane src base

    v4f acc[8][4];
    #pragma unroll
    for (int mf = 0; mf < 8; ++mf)
        #pragma unroll
        for (int nf = 0; nf < 4; ++nf)
            acc[mf][nf] = (v4f){0.f, 0.f, 0.f, 0.f};

    #define STAGE(BUF, TK)                                                    \
        {                                                                     \
            const long kk  = kstart + (long)(TK) * 32;                        \
            const int q128 = (int)(kk >> 7);                                  \
            const int kin  = (int)kk & 127;                                   \
            _Pragma("unroll")                                                 \
            for (int j = 0; j < 2; ++j) {                                     \
                const int r0   = (wave << 5) + (j << 4);   /* 0..240 */       \
                const int half = r0 >> 7;                                     \
                const long lofs = (long)(r0 & 127) * 128 + kin + lsrc;        \
                const int bia = bi2 * 2 + half;                               \
                const __bf16* asrc = (q128 >= bia)                            \
                    ? Apk + (((long)(bia * 32 - (bia * (bia - 1)) / 2 - bia   \
                                     + q128)) << 14) + lofs                   \
                    : Zb + lofs;                                              \
                GLOAD16(&AsF[BUF][r0 << 5], asrc);                            \
                const int bjb = bj2 * 2 + half;                               \
                const __bf16* bsrc = (q128 <= bjb)                            \
                    ? Bpk + (((long)((bjb * (bjb + 1)) / 2 + q128)) << 14)    \
                          + lofs                                              \
                    : Zb + lofs;                                              \
                GLOAD16(&BsF[BUF][r0 << 5], bsrc);                            \
            }                                                                 \
        }

    // prologue: 2 stages in flight (8 vmem ops/wave)
    STAGE(0, 0);
    STAGE(1, 1);

    int cur = 0;
    for (int tk = 0; tk < nt; ++tk) {
        // counted wait: own stage(tk) loads done; stage(tk+1) stays in flight
        if (tk + 1 < nt) { asm volatile("s_waitcnt vmcnt(4)" ::: "memory"); }
        else             { asm volatile("s_waitcnt vmcnt(0)" ::: "memory"); }
        __builtin_amdgcn_sched_barrier(0);
        __builtin_amdgcn_s_barrier();       // all waves: stage(tk) visible,
                                            // compute(tk-1) readers finished
        __builtin_amdgcn_sched_barrier(0);

        int nx = cur + 2; if (nx >= 3) nx -= 3;
        if (tk + 2 < nt) STAGE(nx, tk + 2);   // overwrites buf of tile tk-1

        v8bf af[8], bfv[4];
        #pragma unroll
        for (int nf = 0; nf < 4; ++nf)
            bfv[nf] = *reinterpret_cast<const v8bf*>(
                &BsF[cur][((wc + nf * 16 + l15) << 5) + rdsl]);
        #pragma unroll
        for (int mf = 0; mf < 8; ++mf)
            af[mf] = *reinterpret_cast<const v8bf*>(
                &AsF[cur][((wr + mf * 16 + l15) << 5) + rdsl]);
        #pragma unroll
        for (int mf = 0; mf < 8; ++mf)
            #pragma unroll
            for (int nf = 0; nf < 4; ++nf)
                acc[mf][nf] = __builtin_amdgcn_mfma_f32_16x16x32_bf16(
                    af[mf], bfv[nf], acc[mf][nf], 0, 0, 0);

        cur = (cur + 1 == 3) ? 0 : cur + 1;
    }
    #undef STAGE

    // epilogue: C/D layout col=lane&15, row=(lane>>4)*4+reg
    if (c == 0) {
        float* outp = C + (long)bi2 * 256 * NN + (long)bj2 * 256;
        const bool merged = (S > 1);
        #pragma unroll
        for (int mf = 0; mf < 8; ++mf)
            #pragma unroll
            for (int nf = 0; nf < 4; ++nf) {
                int row = wr + mf * 16 + g * 4;
                int col = wc + nf * 16 + l15;
                #pragma unroll
                for (int r = 0; r < 4; ++r) {
                    float* p = &outp[(long)(row + r) * NN + col];
                    if (merged) *p = acc[mf][nf][r];
                    else        __builtin_nontemporal_store(acc[mf][nf][r], p);
                }
            }
    } else {
        __bf16* pp = part + (long)(sb + bi2 * (S - 1) + (c - 1)) * TILE2_ELEMS;
        #pragma unroll
        for (int mf = 0; mf < 8; ++mf)
            #pragma unroll
            for (int nf = 0; nf < 4; ++nf) {
                int row = wr + mf * 16 + g * 4;
                int col = wc + nf * 16 + l15;
                #pragma unroll
                for (int r = 0; r < 4; ++r)
                    pp[(row + r) * 256 + col] = (__bf16)acc[mf][nf][r];
            }
    }
}

// ------- merge: slice-parallel, 8 blocks per merged 256-tile ----------------
__global__ __launch_bounds__(256)
void trimm_merge(float* __restrict__ C, const __bf16* __restrict__ part, int umax) {
    int rem = blockIdx.x >> 3;
    const int slice = blockIdx.x & 7;
    const int t = threadIdx.x;
    int d2, S, sb = 0;
    for (d2 = NT2 - 1;; --d2) {
        S = (d2 + umax) / umax;
        if (S > 1) {
            int cnt = NT2 - d2;
            if (rem < cnt) break;
            rem -= cnt;
            sb += cnt * (S - 1);
        }
    }
    const int bi2 = rem, bj2 = bi2 + d2;
    const int ns = S - 1;
    const __bf16* pp = part + (long)(sb + bi2 * ns) * TILE2_ELEMS;
    float* cp = C + (long)bi2 * 256 * NN + (long)bj2 * 256;
    const int row0 = slice * 32;

    #pragma unroll
    for (int i = 0; i < 4; ++i) {
        int e = (i * 256 + t) * 8;            // 0..8191 within slice
        int r = row0 + (e >> 8), c8 = e & 255;
        v4f lo = *reinterpret_cast<v4f*>(&cp[(long)r * NN + c8]);
        v4f hi = *reinterpret_cast<v4f*>(&cp[(long)r * NN + c8 + 4]);
        for (int q = 0; q < ns; ++q) {
            v8bf w = *reinterpret_cast<const v8bf*>(
                &pp[(long)q * TILE2_ELEMS + r * 256 + c8]);
            lo[0] += (float)w[0]; lo[1] += (float)w[1];
            lo[2] += (float)w[2]; lo[3] += (float)w[3];
            hi[0] += (float)w[4]; hi[1] += (float)w[5];
            hi[2] += (float)w[6]; hi[3] += (float)w[7];
        }
        __builtin_nontemporal_store(lo, reinterpret_cast<v4f*>(&cp[(long)r * NN + c8]));
        __builtin_nontemporal_store(hi, reinterpret_cast<v4f*>(&cp[(long)r * NN + c8 + 4]));
    }
}

// ---------------- fallback (ws too small): fused convert-stage kernel -------
#define LDST 40
__global__ __launch_bounds__(256)
void trimm_fb(const float* __restrict__ A, const float* __restrict__ B,
              float* __restrict__ C) {
    const int id = blockIdx.x, t = threadIdx.x;
    if (id >= NUPPER) {
        int z = id - NUPPER;
        int bi = 1;
        while (((bi + 1) * bi) / 2 <= z) ++bi;
        int bj = z - (bi * (bi - 1)) / 2;
        const long brow = (long)bi * 128, bcol = (long)bj * 128;
        const v4f zv = (v4f){0.f, 0.f, 0.f, 0.f};
        #pragma unroll
        for (int i = 0; i < 16; ++i) {
            int s = i * 256 + t, r = s >> 5, c4 = (s & 31) << 2;
            *reinterpret_cast<v4f*>(&C[(brow + r) * NN + bcol + c4]) = zv;
        }
        return;
    }
    int q = (NUPPER - 1) - id;
    int d = 0;
    while (d < 31 && 32 * (d + 1) - (d + 1) * d / 2 <= q) ++d;
    const int bi = q - (32 * d - d * (d - 1) / 2);
    const int bj = bi + d;
    const long brow = (long)bi * 128, bcol = (long)bj * 128;
    __shared__ __bf16 As[128][LDST];
    __shared__ __bf16 Bs[128][LDST];
    const int lane = t & 63, wave = t >> 6;
    const int wm = (wave >> 1) * 64, wn = (wave & 1) * 64;
    const int l15 = lane & 15, g = lane >> 4;
    const int arow = t >> 3, akc = (t & 7) << 2;
    const int bn = t & 31, bkc = (t >> 5) << 2;
    v4f acc[4][4];
    #pragma unroll
    for (int mf = 0; mf < 4; ++mf)
        #pragma unroll
        for (int nf = 0; nf < 4; ++nf) acc[mf][nf] = (v4f){0.f,0.f,0.f,0.f};
    const long k0 = brow;
    const int nt = (d + 1) * 4;
    for (int tk = 0; tk < nt; ++tk) {
        const long kt = k0 + (long)tk * 32;
        #pragma unroll
        for (int i = 0; i < 4; ++i) {
            v4f a4 = *reinterpret_cast<const v4f*>(
                &A[(brow + arow + 32 * i) * NN + kt + akc]);
            v4bf pk;
            pk[0]=(__bf16)a4[0]; pk[1]=(__bf16)a4[1]; pk[2]=(__bf16)a4[2]; pk[3]=(__bf16)a4[3];
            *reinterpret_cast<v4bf*>(&As[arow + 32 * i][akc]) = pk;
        }
        {
            float tmp[4][4];
            #pragma unroll
            for (int jj = 0; jj < 4; ++jj) {
                const float* Brow = B + (kt + bkc + jj) * NN + bcol + bn;
                #pragma unroll
                for (int j = 0; j < 4; ++j) tmp[j][jj] = Brow[32 * j];
            }
            #pragma unroll
            for (int j = 0; j < 4; ++j) {
                v4bf pk;
                pk[0]=(__bf16)tmp[j][0]; pk[1]=(__bf16)tmp[j][1];
                pk[2]=(__bf16)tmp[j][2]; pk[3]=(__bf16)tmp[j][3];
                *reinterpret_cast<v4bf*>(&Bs[bn + 32 * j][bkc]) = pk;
            }
        }
        __syncthreads();
        v8bf af[4], bfr[4];
        #pragma unroll
        for (int mf = 0; mf < 4; ++mf)
            af[mf] = *reinterpret_cast<const v8bf*>(&As[wm + mf*16 + l15][g*8]);
        #pragma unroll
        for (int nf = 0; nf < 4; ++nf)
            bfr[nf] = *reinterpret_cast<const v8bf*>(&Bs[wn + nf*16 + l15][g*8]);
        #pragma unroll
        for (int mf = 0; mf < 4; ++mf)
            #pragma unroll
            for (int nf = 0; nf < 4; ++nf)
                acc[mf][nf] = __builtin_amdgcn_mfma_f32_16x16x32_bf16(
                    af[mf], bfr[nf], acc[mf][nf], 0, 0, 0);
        __syncthreads();
    }
    #pragma unroll
    for (int mf = 0; mf < 4; ++mf)
        #pragma unroll
        for (int nf = 0; nf < 4; ++nf) {
            long row = brow + wm + mf * 16 + g * 4;
            long col = bcol + wn + nf * 16 + l15;
            #pragma unroll
            for (int r = 0; r < 4; ++r)
                C[(row + r) * NN + col] = acc[mf][nf][r];
        }
}

static void split_counts2(int umax, int* nwork, int* slots, int* mtiles) {
    int w = 0, s = 0, m = 0;
    for (int d = 0; d < NT2; ++d) {
        int S = (d + umax) / umax;
        w += (NT2 - d) * S;
        s += (NT2 - d) * (S - 1);
        if (S > 1) m += (NT2 - d);
    }
    *nwork = w; *slots = s; *mtiles = m;
}

extern "C" void kernel_launch(void* const* d_in, const int* in_sizes, int n_in,
                              void* d_out, int out_size, void* d_ws, size_t ws_size,
                              hipStream_t stream) {
    const float* A = (const float*)d_in[0];
    const float* B = (const float*)d_in[1];
    float* C = (float*)d_out;

    const size_t elemsAB = 2UL * NUPPER * BLK_ELEMS;                 // bf16 elems
    const size_t needBase = (elemsAB + ZB_ELEMS) * sizeof(__bf16);   // ~33.1 MB

    const int cand[3] = {3, 5, 1000};
    int umax = 0, nwork = 0, slots = 0, mtiles = 0;
    for (int i = 0; i < 3; ++i) {
        int w, s, m;
        split_counts2(cand[i], &w, &s, &m);
        size_t need = needBase + (size_t)s * TILE2_ELEMS * sizeof(__bf16);
        if (ws_size >= need) { umax = cand[i]; nwork = w; slots = s; mtiles = m; break; }
    }

    if (umax) {
        __bf16* Apk = (__bf16*)d_ws;
        __bf16* Bpk = Apk + (size_t)NUPPER * BLK_ELEMS;
        __bf16* Zb  = Bpk + (size_t)NUPPER * BLK_ELEMS;
        __bf16* part = Zb + ZB_ELEMS;
        trimm_prep<<<dim3(2 * NUPPER + NLOWER + 1), 256, 0, stream>>>(
            A, B, C, Apk, Bpk, Zb);
        trimm_mm<<<dim3(nwork), 512, 0, stream>>>(Apk, Bpk, Zb, C, part, umax);
        if (slots > 0)
            trimm_merge<<<dim3(mtiles * 8), 256, 0, stream>>>(C, part, umax);
    } else {
        trimm_fb<<<dim3(NUPPER + NLOWER), 256, 0, stream>>>(A, B, C);
    }
}